// Round 1
// baseline (554.496 us; speedup 1.0000x reference)
//
#include <hip/hip_runtime.h>
#include <stdint.h>

// TPTransMatrix: out = x (16384 x 4096) times block_diag(blocks[0..7]) where
// blocks[kb] is 512x512. Grouped bf16-MFMA GEMM: M=16384, K=512, N=512, x8 groups.

#define HID 4096
#define KD  512
#define NKB 8
#define BM  128
#define BN  128
#define BK  32
#define MTILES 128            // 16384 / BM
#define ASTRIDE 40            // A LDS row stride in uint16 (80 B: 64 used + 16 pad)

typedef __attribute__((ext_vector_type(4))) float    f32x4;
typedef __attribute__((ext_vector_type(8))) short    s16x8;
typedef __attribute__((ext_vector_type(4))) uint32_t u32x4;

// bf16 transposed copy of blocks: g_bt[kb][c][b] = bf16(blocks[kb][b][c]).
// Static device array instead of d_ws so we don't depend on ws_size (4 MB).
__device__ uint16_t g_bt[(size_t)NKB * KD * KD];

__device__ __forceinline__ void async_copy16(const void* g, void* l) {
  __builtin_amdgcn_global_load_lds((const __attribute__((address_space(1))) void*)g,
                                   (__attribute__((address_space(3))) void*)l,
                                   16, 0, 0);
}

// fp32 -> bf16 RNE
__device__ __forceinline__ uint16_t f2bf_rne(float f) {
  uint32_t u = __float_as_uint(f);
  u += 0x7fffu + ((u >> 16) & 1u);
  return (uint16_t)(u >> 16);
}

// ---------------- prep: transpose + convert blocks -> g_bt ----------------
__global__ void convert_blocks_k(const float* __restrict__ blocks) {
  __shared__ float tile[32][33];                 // +1 pad: conflict-free transpose
  const int kb = blockIdx.z;
  const int c0 = blockIdx.x * 32;
  const int b0 = blockIdx.y * 32;
  const int tx = threadIdx.x;                    // 0..31
  const int ty = threadIdx.y;                    // 0..7
  const float* src = blocks + ((size_t)kb * KD + b0) * KD + c0;
#pragma unroll
  for (int i = 0; i < 4; ++i) {
    const int r = ty + i * 8;
    tile[r][tx] = src[(size_t)r * KD + tx];      // coalesced in c
  }
  __syncthreads();
  uint16_t* dst = g_bt + ((size_t)kb * KD + c0) * KD + b0;
#pragma unroll
  for (int i = 0; i < 4; ++i) {
    const int r = ty + i * 8;
    dst[(size_t)r * KD + tx] = f2bf_rne(tile[tx][r]);   // coalesced in b
  }
}

// ---------------- main grouped GEMM ----------------
__global__ void grouped_gemm_k(const float* __restrict__ x, float* __restrict__ out) {
  __shared__ uint16_t lA[BM * ASTRIDE];   // bf16 A tile, padded rows (2-way-free frag reads)
  __shared__ uint16_t lB[BN * BK];        // bf16 Bt tile, xor-swizzled 16B slots

  const int tid = threadIdx.x;
  const int wg  = blockIdx.x;
  const int nt  =  wg       & 3;          // n-tile fastest: 4 consecutive WGs share A slice (LLC)
  const int kb  = (wg >> 2) & 7;
  const int mt  =  wg >> 5;

  const int wave = tid >> 6;
  const int lane = tid & 63;
  const int ln   = lane & 15;
  const int qd   = lane >> 4;
  const int wm   = (wave & 1) * 64;
  const int wn   = (wave >> 1) * 64;

  // ---- A staging: thread -> (row am, k-half ah), 16 consecutive floats (64 B) ----
  const int am = tid >> 1;
  const int ah = tid & 1;
  const float* aptr = x + (size_t)(mt * BM + am) * HID + kb * KD + ah * 16;
  uint16_t* awr = lA + am * ASTRIDE + ah * 16;   // two 16B slots at +0, +8 (uint16 units)

  // ---- B staging: slots p = tid, tid+256; swizzle lives on the global-address side ----
  const int bn0 = tid >> 2;
  const int bs0 = (tid & 3) ^ (bn0 & 3) ^ ((bn0 >> 2) & 3);
  const int p1  = tid + 256;
  const int bn1 = p1 >> 2;
  const int bs1 = (p1 & 3) ^ (bn1 & 3) ^ ((bn1 >> 2) & 3);
  const uint16_t* bsrc0 = g_bt + (size_t)(kb * KD + nt * BN + bn0) * KD + bs0 * 8;
  const uint16_t* bsrc1 = g_bt + (size_t)(kb * KD + nt * BN + bn1) * KD + bs1 * 8;
  uint16_t* bdst0 = lB + tid * 8;                // lane-contiguous: required by global_load_lds
  uint16_t* bdst1 = lB + p1 * 8;

  // ---- fragment read bases ----
  const int sw = (ln & 3) ^ ((ln >> 2) & 3);     // matches staging swizzle (n bits == ln bits)
  const uint16_t* ard = lA + (wm + ln) * ASTRIDE + qd * 8;
  const uint16_t* brd = lB + ((wn + ln) * 4 + (qd ^ sw)) * 8;

  f32x4 acc[4][4];
#pragma unroll
  for (int mi = 0; mi < 4; ++mi)
#pragma unroll
    for (int ni = 0; ni < 4; ++ni)
      acc[mi][ni] = (f32x4){0.f, 0.f, 0.f, 0.f};

  for (int kk = 0; kk < KD / BK; ++kk) {
    const int k0 = kk * BK;
    // issue A global loads before the barrier so they fly during the wait
    const f32x4 a0 = *(const f32x4*)(aptr + k0);
    const f32x4 a1 = *(const f32x4*)(aptr + k0 + 4);
    const f32x4 a2 = *(const f32x4*)(aptr + k0 + 8);
    const f32x4 a3 = *(const f32x4*)(aptr + k0 + 12);

    __syncthreads();   // previous iter's frag reads done before overwrite

    async_copy16(bsrc0 + k0, bdst0);
    async_copy16(bsrc1 + k0, bdst1);

    // fp32 -> bf16 truncate-pack: 1 v_perm_b32 per 2 elements
    u32x4 w0, w1;
    w0.x = __builtin_amdgcn_perm(__float_as_uint(a0.y), __float_as_uint(a0.x), 0x07060302u);
    w0.y = __builtin_amdgcn_perm(__float_as_uint(a0.w), __float_as_uint(a0.z), 0x07060302u);
    w0.z = __builtin_amdgcn_perm(__float_as_uint(a1.y), __float_as_uint(a1.x), 0x07060302u);
    w0.w = __builtin_amdgcn_perm(__float_as_uint(a1.w), __float_as_uint(a1.z), 0x07060302u);
    w1.x = __builtin_amdgcn_perm(__float_as_uint(a2.y), __float_as_uint(a2.x), 0x07060302u);
    w1.y = __builtin_amdgcn_perm(__float_as_uint(a2.w), __float_as_uint(a2.z), 0x07060302u);
    w1.z = __builtin_amdgcn_perm(__float_as_uint(a3.y), __float_as_uint(a3.x), 0x07060302u);
    w1.w = __builtin_amdgcn_perm(__float_as_uint(a3.w), __float_as_uint(a3.z), 0x07060302u);
    *(u32x4*)(awr)     = w0;
    *(u32x4*)(awr + 8) = w1;

    __syncthreads();   // drains vmcnt (global_load_lds) + lgkm (ds_write)

    s16x8 af[4], bf[4];
#pragma unroll
    for (int mi = 0; mi < 4; ++mi) af[mi] = *(const s16x8*)(ard + mi * (16 * ASTRIDE));
#pragma unroll
    for (int ni = 0; ni < 4; ++ni) bf[ni] = *(const s16x8*)(brd + ni * (16 * 32));
#pragma unroll
    for (int mi = 0; mi < 4; ++mi)
#pragma unroll
      for (int ni = 0; ni < 4; ++ni)
        acc[mi][ni] = __builtin_amdgcn_mfma_f32_16x16x32_bf16(af[mi], bf[ni], acc[mi][ni], 0, 0, 0);
  }

  // epilogue: C/D layout col=lane&15, row=quad*4+reg (m89-verified)
  const int col = kb * KD + nt * BN + wn + ln;
#pragma unroll
  for (int mi = 0; mi < 4; ++mi) {
    const int row0 = mt * BM + wm + mi * 16 + qd * 4;
#pragma unroll
    for (int r = 0; r < 4; ++r) {
      float* orow = out + (size_t)(row0 + r) * HID + col;
#pragma unroll
      for (int ni = 0; ni < 4; ++ni)
        orow[ni * 16] = acc[mi][ni][r];
    }
  }
}

extern "C" void kernel_launch(void* const* d_in, const int* in_sizes, int n_in,
                              void* d_out, int out_size, void* d_ws, size_t ws_size,
                              hipStream_t stream) {
  const float* x      = (const float*)d_in[0];   // [4,4096,4096] fp32 = 16384 x 4096
  const float* blocks = (const float*)d_in[1];   // [8,512,512] fp32
  float* out = (float*)d_out;
  (void)d_ws; (void)ws_size; (void)in_sizes; (void)n_in; (void)out_size;

  convert_blocks_k<<<dim3(16, 16, 8), dim3(32, 8, 1), 0, stream>>>(blocks);
  grouped_gemm_k<<<dim3(MTILES * NKB * 4, 1, 1), dim3(256, 1, 1), 0, stream>>>(x, out);
}